// Round 2
// baseline (886.852 us; speedup 1.0000x reference)
//
#include <hip/hip_runtime.h>
#include <math.h>

// Problem constants: N=100000, E=400000, G=64, IN=8, H=4, C=64, HD=256.
// Workspace budget: bufA (N*256*4=102.4MB) + bufXL (102.4MB) + h0 (25.6MB)
// + CSR (~2.5MB) ~= 233 MB total (previous 310MB version core-dumped; suspect
// ws_size overflow).

#define HD 256
#define NHEAD 4
#define CH 64

// ---------------------------------------------------------------------------
__global__ void zero_int(int* __restrict__ p, int n) {
    int i = blockIdx.x * 256 + threadIdx.x;
    if (i < n) p[i] = 0;
}

// ---------------------------------------------------------------------------
// CSR build: degree histogram -> 3-step exclusive scan -> scatter
// ---------------------------------------------------------------------------
__global__ void deg_kernel(const int* __restrict__ dst, int* __restrict__ cnt, int E) {
    int e = blockIdx.x * 256 + threadIdx.x;
    if (e < E) atomicAdd(&cnt[dst[e]], 1);
}

__global__ void scan_block(const int* __restrict__ cnt, int* __restrict__ off,
                           int* __restrict__ bsum, int N) {
    __shared__ int s[256];
    int i = blockIdx.x * 256 + threadIdx.x;
    int v = (i < N) ? cnt[i] : 0;
    s[threadIdx.x] = v;
    __syncthreads();
    for (int d = 1; d < 256; d <<= 1) {
        int t = 0;
        if (threadIdx.x >= d) t = s[threadIdx.x - d];
        __syncthreads();
        s[threadIdx.x] += t;
        __syncthreads();
    }
    if (i < N) off[i + 1] = s[threadIdx.x];            // within-block inclusive
    if (threadIdx.x == 255) bsum[blockIdx.x] = s[255];
    if (blockIdx.x == 0 && threadIdx.x == 0) off[0] = 0;
}

__global__ void scan_bsum(const int* __restrict__ bsum, int* __restrict__ bpre, int nb) {
    __shared__ int s[512];
    int t = threadIdx.x;
    s[t] = (t < nb) ? bsum[t] : 0;
    __syncthreads();
    for (int d = 1; d < 512; d <<= 1) {
        int x = 0;
        if (t >= d) x = s[t - d];
        __syncthreads();
        s[t] += x;
        __syncthreads();
    }
    if (t < nb) bpre[t] = s[t] - bsum[t];              // exclusive prefix of block sums
}

__global__ void scan_add(int* __restrict__ off, const int* __restrict__ bpre, int N) {
    int i = blockIdx.x * 256 + threadIdx.x;
    if (i < N) off[i + 1] += bpre[blockIdx.x];
}

__global__ void scatter_kernel(const int* __restrict__ dst, const int* __restrict__ off,
                               int* __restrict__ cur, int* __restrict__ eidx, int E) {
    int e = blockIdx.x * 256 + threadIdx.x;
    if (e < E) {
        int d = dst[e];
        int p = atomicAdd(&cur[d], 1);
        eidx[off[d] + p] = e;
    }
}

// ---------------------------------------------------------------------------
// Encoder: h0[N,64] = relu(x[N,8] @ W_enc[8,64] + b_enc)
// ---------------------------------------------------------------------------
__global__ void encoder_kernel(const float* __restrict__ x, const float* __restrict__ W,
                               const float* __restrict__ b, float* __restrict__ h, int N) {
    int idx = blockIdx.x * 256 + threadIdx.x;
    if (idx >= N * 64) return;
    int n = idx >> 6, c = idx & 63;
    float v = b[c];
#pragma unroll
    for (int k = 0; k < 8; ++k) v = fmaf(x[n * 8 + k], W[k * 64 + c], v);
    h[idx] = fmaxf(v, 0.f);
}

// ---------------------------------------------------------------------------
// Fused dual GEMM: outL/outR[N,256] = A[N,K] @ {Wl,Wr} + {bl,br}.
// Thread = output column, block = 16 rows. A rows are wave-uniform ->
// scalar loads; W streamed via coalesced vector loads (L2-resident).
// outR may ALIAS A (in-place): block reads all 16 of its A rows before
// storing, and no other block reads those rows -> race-free. No __restrict__
// on A/outR for that reason.
// ---------------------------------------------------------------------------
template <int K>
__global__ __launch_bounds__(256) void gemm_fused(
    const float* A,
    const float* __restrict__ Wl, const float* __restrict__ bl, float* __restrict__ outL,
    const float* __restrict__ Wr, const float* __restrict__ br, float* outR) {
    const int c = threadIdx.x;
    const int row0 = blockIdx.x * 16;

    float accL[16], accR[16];
#pragma unroll
    for (int r = 0; r < 16; ++r) { accL[r] = 0.f; accR[r] = 0.f; }

    const float* Ab = A + (size_t)row0 * K;
    for (int k0 = 0; k0 < K; k0 += 4) {
        float wl[4], wr[4];
#pragma unroll
        for (int u = 0; u < 4; ++u) {
            wl[u] = Wl[(size_t)(k0 + u) * 256 + c];
            wr[u] = Wr[(size_t)(k0 + u) * 256 + c];
        }
#pragma unroll
        for (int r = 0; r < 16; ++r) {
#pragma unroll
            for (int u = 0; u < 4; ++u) {
                float a = Ab[(size_t)r * K + k0 + u];
                accL[r] = fmaf(a, wl[u], accL[r]);
                accR[r] = fmaf(a, wr[u], accR[r]);
            }
        }
    }
    float bbl = bl[c], bbr = br[c];
#pragma unroll
    for (int r = 0; r < 16; ++r) {
        outL[(size_t)(row0 + r) * 256 + c] = accL[r] + bbl;
        outR[(size_t)(row0 + r) * 256 + c] = accR[r] + bbr;
    }
}

// ---------------------------------------------------------------------------
// GATv2 aggregation: one 64-lane wave per destination node, lane = channel.
// Online softmax over incoming edges; single gather pass; no atomics.
// out may ALIAS xr (in-place): node i's xr slot is read only by node i's wave,
// before that same wave writes out[i]. xl is a distinct buffer.
// ---------------------------------------------------------------------------
__global__ __launch_bounds__(256) void gat_aggregate(
    const float* __restrict__ xl, const float* xr,
    const float* __restrict__ eattr, const int* __restrict__ src,
    const int* __restrict__ off, const int* __restrict__ eidx,
    const float* __restrict__ We, const float* __restrict__ att,
    const float* __restrict__ bias, float* out, int N) {
    int node = blockIdx.x * 4 + (threadIdx.x >> 6);
    if (node >= N) return;
    int lane = threadIdx.x & 63;

    float we[NHEAD], at[NHEAD], xrv[NHEAD], m[NHEAD], l[NHEAD], acc[NHEAD];
    size_t nb = (size_t)node * HD;
#pragma unroll
    for (int h = 0; h < NHEAD; ++h) {
        we[h] = We[h * CH + lane];
        at[h] = att[h * CH + lane];
        xrv[h] = xr[nb + h * CH + lane];
        m[h] = -1e30f;
        l[h] = 0.f;
        acc[h] = 0.f;
    }
    int s0 = off[node], s1 = off[node + 1];
    for (int t = s0; t < s1; ++t) {
        int ed = eidx[t];
        int j = src[ed];
        float ea = eattr[ed];
        size_t jb = (size_t)j * HD;
        float xlv[NHEAD], lg[NHEAD];
#pragma unroll
        for (int h = 0; h < NHEAD; ++h) {
            xlv[h] = xl[jb + h * CH + lane];
            float v = fmaf(ea, we[h], xlv[h] + xrv[h]);
            v = (v >= 0.f) ? v : 0.2f * v;   // leaky_relu(0.2)
            lg[h] = at[h] * v;
        }
#pragma unroll
        for (int h = 0; h < NHEAD; ++h) {
            float r = lg[h];
            for (int o = 32; o > 0; o >>= 1) r += __shfl_xor(r, o);
            float mn = fmaxf(m[h], r);
            float sc = expf(m[h] - mn);
            float p = expf(r - mn);
            l[h] = fmaf(l[h], sc, p);
            acc[h] = fmaf(acc[h], sc, p * xlv[h]);
            m[h] = mn;
        }
    }
#pragma unroll
    for (int h = 0; h < NHEAD; ++h) {
        float o = acc[h] / (l[h] + 1e-16f) + bias[h * CH + lane];
        out[nb + h * CH + lane] = fmaxf(o, 0.f);
    }
}

// ---------------------------------------------------------------------------
// Global mean pool (batch is sorted): 8 partial blocks per graph, atomicAdd
// into pooled[64][256] (pre-zeroed).
// ---------------------------------------------------------------------------
__device__ __forceinline__ int lowerb(const int* b, int n, int v) {
    int lo = 0, hi = n;
    while (lo < hi) {
        int mid = (lo + hi) >> 1;
        if (b[mid] < v) lo = mid + 1; else hi = mid;
    }
    return lo;
}

__global__ void pool_kernel(const float* __restrict__ h, const int* __restrict__ batch,
                            float* __restrict__ pooled, float* __restrict__ gcnt, int N) {
    int g = blockIdx.x >> 3, part = blockIdx.x & 7;
    int start = lowerb(batch, N, g);
    int end = lowerb(batch, N, g + 1);
    int rows = end - start;
    int r0 = start + (int)((long long)rows * part / 8);
    int r1 = start + (int)((long long)rows * (part + 1) / 8);
    int c = threadIdx.x;
    float s = 0.f;
    for (int r = r0; r < r1; ++r) s += h[(size_t)r * HD + c];
    atomicAdd(&pooled[g * HD + c], s);
    if (part == 0 && c == 0) gcnt[g] = (float)rows;
}

// ---------------------------------------------------------------------------
// Post MLP: mean -> 256->128 -> LayerNorm -> relu -> 128->64 -> relu -> 64->1
// One block (128 threads) per graph.
// ---------------------------------------------------------------------------
__global__ void mlp_kernel(const float* __restrict__ pooled, const float* __restrict__ gcnt,
                           const float* __restrict__ W_p1, const float* __restrict__ b_p1,
                           const float* __restrict__ ln_g, const float* __restrict__ ln_b,
                           const float* __restrict__ W_p2, const float* __restrict__ b_p2,
                           const float* __restrict__ W_head, const float* __restrict__ b_head,
                           float* __restrict__ out) {
    int g = blockIdx.x;
    int j = threadIdx.x;
    __shared__ float sh[128];
    __shared__ float red[2];

    float inv = 1.f / fmaxf(gcnt[g], 1.f);
    float v = b_p1[j];
    for (int k = 0; k < 256; ++k) v = fmaf(pooled[g * 256 + k] * inv, W_p1[k * 128 + j], v);

    // LayerNorm over 128 (2 waves)
    float s = v;
    for (int o = 32; o > 0; o >>= 1) s += __shfl_xor(s, o);
    if ((j & 63) == 0) red[j >> 6] = s;
    __syncthreads();
    float mu = (red[0] + red[1]) * (1.f / 128.f);
    float d = v - mu;
    float s2 = d * d;
    for (int o = 32; o > 0; o >>= 1) s2 += __shfl_xor(s2, o);
    __syncthreads();
    if ((j & 63) == 0) red[j >> 6] = s2;
    __syncthreads();
    float var = (red[0] + red[1]) * (1.f / 128.f);

    float p = d * rsqrtf(var + 1e-5f) * ln_g[j] + ln_b[j];
    sh[j] = fmaxf(p, 0.f);
    __syncthreads();

    if (j < 64) {
        float q = b_p2[j];
        for (int k = 0; k < 128; ++k) q = fmaf(sh[k], W_p2[k * 64 + j], q);
        q = fmaxf(q, 0.f);
        float t = q * W_head[j];
        for (int o = 32; o > 0; o >>= 1) t += __shfl_xor(t, o);
        if (j == 0) out[g] = t + b_head[0];
    }
}

// ---------------------------------------------------------------------------
extern "C" void kernel_launch(void* const* d_in, const int* in_sizes, int n_in,
                              void* d_out, int out_size, void* d_ws, size_t ws_size,
                              hipStream_t stream) {
    const float* x      = (const float*)d_in[0];
    const float* eattr  = (const float*)d_in[1];
    const int*   src    = (const int*)d_in[2];
    const int*   dst    = (const int*)d_in[3];
    const int*   batch  = (const int*)d_in[4];
    const float* W_enc  = (const float*)d_in[5];
    const float* b_enc  = (const float*)d_in[6];
    const float* g1_Wl  = (const float*)d_in[7];
    const float* g1_bl  = (const float*)d_in[8];
    const float* g1_Wr  = (const float*)d_in[9];
    const float* g1_br  = (const float*)d_in[10];
    const float* g1_We  = (const float*)d_in[11];
    const float* g1_att = (const float*)d_in[12];
    const float* g1_bias= (const float*)d_in[13];
    const float* g2_Wl  = (const float*)d_in[14];
    const float* g2_bl  = (const float*)d_in[15];
    const float* g2_Wr  = (const float*)d_in[16];
    const float* g2_br  = (const float*)d_in[17];
    const float* g2_We  = (const float*)d_in[18];
    const float* g2_att = (const float*)d_in[19];
    const float* g2_bias= (const float*)d_in[20];
    const float* W_p1   = (const float*)d_in[21];
    const float* b_p1   = (const float*)d_in[22];
    const float* ln_g   = (const float*)d_in[23];
    const float* ln_b   = (const float*)d_in[24];
    const float* W_p2   = (const float*)d_in[25];
    const float* b_p2   = (const float*)d_in[26];
    const float* W_head = (const float*)d_in[27];
    const float* b_head = (const float*)d_in[28];

    const int N = in_sizes[0] / 8;   // 100000
    const int E = in_sizes[2];       // 400000

    // workspace layout (~233 MB)
    char* p = (char*)d_ws;
    auto alloc = [&](size_t bytes) -> void* {
        void* r = (void*)p;
        p += (bytes + 255) & ~(size_t)255;
        return r;
    };
    float* bufA   = (float*)alloc((size_t)N * HD * 4);   // XR / h (in-place chain)
    float* bufXL  = (float*)alloc((size_t)N * HD * 4);   // XL (gather target)
    float* bufH0  = (float*)alloc((size_t)N * CH * 4);   // encoder output
    int*   cnt    = (int*)alloc((size_t)N * 4);
    int*   off    = (int*)alloc((size_t)(N + 1) * 4);
    int*   eidx   = (int*)alloc((size_t)E * 4);
    const int nb  = (N + 255) / 256;
    int*   bsum   = (int*)alloc((size_t)nb * 4);
    int*   bpre   = (int*)alloc((size_t)nb * 4);
    float* pooled = (float*)alloc(64 * HD * 4);
    float* gcnt   = (float*)alloc(64 * 4);

    // ---- CSR by dst (built once, reused for both GAT layers) ----
    zero_int<<<nb, 256, 0, stream>>>(cnt, N);
    deg_kernel<<<(E + 255) / 256, 256, 0, stream>>>(dst, cnt, E);
    scan_block<<<nb, 256, 0, stream>>>(cnt, off, bsum, N);
    scan_bsum<<<1, 512, 0, stream>>>(bsum, bpre, nb);
    scan_add<<<nb, 256, 0, stream>>>(off, bpre, N);
    zero_int<<<nb, 256, 0, stream>>>(cnt, N);
    scatter_kernel<<<(E + 255) / 256, 256, 0, stream>>>(dst, off, cnt, eidx, E);

    // ---- encoder ----
    encoder_kernel<<<(N * 64 + 255) / 256, 256, 0, stream>>>(x, W_enc, b_enc, bufH0, N);

    // ---- GAT layer 1: h0 -> XL(bufXL), XR(bufA); aggregate -> h1 in-place(bufA)
    gemm_fused<64><<<N / 16, 256, 0, stream>>>(
        bufH0, g1_Wl, g1_bl, bufXL, g1_Wr, g1_br, bufA);
    gat_aggregate<<<(N + 3) / 4, 256, 0, stream>>>(
        bufXL, bufA, eattr, src, off, eidx, g1_We, g1_att, g1_bias, bufA, N);

    // ---- GAT layer 2: h1(bufA) -> XL(bufXL), XR in-place(bufA); aggregate -> h2(bufA)
    gemm_fused<256><<<N / 16, 256, 0, stream>>>(
        bufA, g2_Wl, g2_bl, bufXL, g2_Wr, g2_br, bufA);
    gat_aggregate<<<(N + 3) / 4, 256, 0, stream>>>(
        bufXL, bufA, eattr, src, off, eidx, g2_We, g2_att, g2_bias, bufA, N);

    // ---- pool + MLP head ----
    zero_int<<<(64 * HD + 255) / 256, 256, 0, stream>>>((int*)pooled, 64 * HD);
    pool_kernel<<<64 * 8, 256, 0, stream>>>(bufA, batch, pooled, gcnt, N);
    mlp_kernel<<<64, 128, 0, stream>>>(pooled, gcnt, W_p1, b_p1, ln_g, ln_b,
                                       W_p2, b_p2, W_head, b_head, (float*)d_out);
}